// Round 11
// baseline (1322.198 us; speedup 1.0000x reference)
//
#include <hip/hip_runtime.h>
#include <hip/hip_bf16.h>
#include <cstdint>
#include <cstddef>

// ---------------------------------------------------------------------------
// Attention block: qkv = x @ wqkv^T ; rope(q,k) ; causal GQA attention ; out = att @ wo^T
// B=1, S=2048, DIM=4096, NH=32, NKV=8, HD=128. All compute in bf16 MFMA + f32 accum.
// ---------------------------------------------------------------------------

typedef __attribute__((ext_vector_type(4)))  float    f32x4;
typedef __attribute__((ext_vector_type(16))) float    f32x16;
typedef __attribute__((ext_vector_type(8)))  __bf16   bf16x8;
typedef __attribute__((ext_vector_type(4)))  __bf16   bf16x4;
typedef __attribute__((ext_vector_type(2)))  __bf16   bf16x2;
typedef __attribute__((ext_vector_type(4)))  uint32_t u32x4;

typedef const __attribute__((address_space(1))) void* gaddr_t;
typedef __attribute__((address_space(3))) void*       laddr_t;

#define S_LEN   2048
#define DIM_    4096
#define NHEADS  32
#define NKV     8
#define HD      128
#define QKV_LD  6144   // row stride of qkv buffer (Q|K|V)
#define KOFF    4096
#define VOFF    5120

#define EXP2F(x) __builtin_amdgcn_exp2f(x)   // v_exp_f32 (2^x); __exp2f collides with glibc macro

// ---------------- f32 -> bf16 conversion (vectorized x4) -------------------
__global__ void cvt_f32_bf16(const float* __restrict__ in, __bf16* __restrict__ out, int n4) {
  int idx = blockIdx.x * blockDim.x + threadIdx.x;
  int stride = gridDim.x * blockDim.x;
  for (int i = idx; i < n4; i += stride) {
    float4 v = reinterpret_cast<const float4*>(in)[i];
    bf16x4 o;
    o[0] = (__bf16)v.x; o[1] = (__bf16)v.y; o[2] = (__bf16)v.z; o[3] = (__bf16)v.w;
    reinterpret_cast<bf16x4*>(out)[i] = o;
  }
}

// ---------------- RoPE in-place on Q and K parts of qkv --------------------
__global__ void rope_kernel(__bf16* __restrict__ qkv, const float* __restrict__ fc,
                            const float* __restrict__ fs) {
  int tid = blockIdx.x * 256 + threadIdx.x;   // 0 .. 2048*40*64-1
  int i = tid & 63;
  int t = tid >> 6;
  int h = t % 40;
  int s = t / 40;
  int col = (h < NHEADS) ? (h * HD + 2 * i) : (KOFF + (h - NHEADS) * HD + 2 * i);
  size_t off = (size_t)s * QKV_LD + col;
  float c = fc[s * 64 + i], sn = fs[s * 64 + i];
  bf16x2 v = *reinterpret_cast<bf16x2*>(&qkv[off]);
  float t0 = (float)v[0], t1 = (float)v[1];
  bf16x2 o;
  o[0] = (__bf16)(t0 * c - t1 * sn);
  o[1] = (__bf16)(t0 * sn + t1 * c);
  *reinterpret_cast<bf16x2*>(&qkv[off]) = o;
}

// ---------------- counted-vmcnt 32x32 GEMM: C = A[M,K] * B[N,K]^T ----------
// 512 thr = 8 waves (2M x 4N), BM=256, BN=NI*128, BK=64. Per-wave 128 x NI*32.
// B fragments read ONCE per K-tile (held in registers across both phases) ->
// per-wave LDS = 24KB/K-tile (structural minimum). Double-buffered LDS,
// half-tile staggered staging in FIFO [A0,A0,B0,B1,(B2,B3),A1,A1]; waits:
// phase0 vmcnt(2), phase1 vmcnt(4) steady / (2,0) last tile — loads always
// have >=1 full phase of cover and >=2 half-tiles stay in flight (T4).
template <int N> __device__ __forceinline__ void vmwait() {
  if constexpr (N == 0) asm volatile("s_waitcnt vmcnt(0)" ::: "memory");
  else if constexpr (N == 2) asm volatile("s_waitcnt vmcnt(2)" ::: "memory");
  else asm volatile("s_waitcnt vmcnt(4)" ::: "memory");
}

// one stage op: 64 rows x 128B (512 thr x 16B), linear LDS rows, swizzled src
__device__ __forceinline__ void stg(const __bf16* __restrict__ P, int ld, int grow0,
                                    int kt, char* dst, int tid) {
  int r = tid >> 3, g = tid & 7;
  int row = grow0 + r;
  const __bf16* src = P + (size_t)row * ld + kt * 64 + ((g ^ (row & 7)) * 8);
  __builtin_amdgcn_global_load_lds((gaddr_t)src,
      (laddr_t)(dst + (tid & ~63) * 16), 16, 0, 0);
}

template <int NI, int WAIT, bool ST>
__device__ __forceinline__ void phase0(const __bf16* __restrict__ Ab,
                                       const __bf16* __restrict__ Bb,
                                       f32x16 (&acc)[4][NI], bf16x8 (&bfr)[NI][4],
                                       int wm, int wn, int l31, int hi, int tid,
                                       const __bf16* __restrict__ A, int lda, int m0, char* dA,
                                       const __bf16* __restrict__ B, int ldb, int n0, char* dB,
                                       int kt) {
  vmwait<WAIT>();
  __builtin_amdgcn_s_barrier();
  bf16x8 af[2][4];
#pragma unroll
  for (int mi = 0; mi < 2; ++mi) {
    int R = wm * 128 + mi * 32 + l31;                 // A-half0 rows
#pragma unroll
    for (int s = 0; s < 4; ++s)
      af[mi][s] = *reinterpret_cast<const bf16x8*>(
          (const char*)Ab + R * 128 + (((s * 2 + hi) ^ (R & 7)) * 16));
  }
#pragma unroll
  for (int ni = 0; ni < NI; ++ni) {                   // ALL B frags (held for phase1)
    int R = wn * (NI * 32) + ni * 32 + l31;
#pragma unroll
    for (int s = 0; s < 4; ++s)
      bfr[ni][s] = *reinterpret_cast<const bf16x8*>(
          (const char*)Bb + R * 128 + (((s * 2 + hi) ^ (R & 7)) * 16));
  }
  if constexpr (ST) {                                 // FIFO: A0,A0,B0,B1
    stg(A, lda, m0,       kt, dA,             tid);
    stg(A, lda, m0 + 128, kt, dA + 128 * 128, tid);
    stg(B, ldb, n0,       kt, dB,             tid);
    stg(B, ldb, n0 + 64,  kt, dB + 64 * 128,  tid);
  }
  asm volatile("s_waitcnt lgkmcnt(0)" ::: "memory");
  __builtin_amdgcn_sched_barrier(0);
  __builtin_amdgcn_s_setprio(1);
#pragma unroll
  for (int s = 0; s < 4; ++s)
#pragma unroll
    for (int mi = 0; mi < 2; ++mi)
#pragma unroll
      for (int ni = 0; ni < NI; ++ni)
        acc[mi][ni] = __builtin_amdgcn_mfma_f32_32x32x16_bf16(af[mi][s], bfr[ni][s],
                                                              acc[mi][ni], 0, 0, 0);
  __builtin_amdgcn_s_setprio(0);
}

template <int NI, int WAIT, bool ST>
__device__ __forceinline__ void phase1(const __bf16* __restrict__ Ab,
                                       f32x16 (&acc)[4][NI], bf16x8 (&bfr)[NI][4],
                                       int wm, int l31, int hi, int tid,
                                       const __bf16* __restrict__ A, int lda, int m0, char* dA,
                                       const __bf16* __restrict__ B, int ldb, int n0, char* dB,
                                       int kt) {
  vmwait<WAIT>();
  __builtin_amdgcn_s_barrier();
  bf16x8 af[2][4];
#pragma unroll
  for (int mi = 0; mi < 2; ++mi) {
    int R = wm * 128 + 64 + mi * 32 + l31;            // A-half1 rows
#pragma unroll
    for (int s = 0; s < 4; ++s)
      af[mi][s] = *reinterpret_cast<const bf16x8*>(
          (const char*)Ab + R * 128 + (((s * 2 + hi) ^ (R & 7)) * 16));
  }
  if constexpr (ST) {                                 // FIFO: (B2,B3),A1,A1
    if constexpr (NI == 2) {
      stg(B, ldb, n0 + 128, kt, dB + 128 * 128, tid);
      stg(B, ldb, n0 + 192, kt, dB + 192 * 128, tid);
    }
    stg(A, lda, m0 + 64,  kt, dA + 64 * 128,  tid);
    stg(A, lda, m0 + 192, kt, dA + 192 * 128, tid);
  }
  asm volatile("s_waitcnt lgkmcnt(0)" ::: "memory");
  __builtin_amdgcn_sched_barrier(0);
  __builtin_amdgcn_s_setprio(1);
#pragma unroll
  for (int s = 0; s < 4; ++s)
#pragma unroll
    for (int mi = 0; mi < 2; ++mi)
#pragma unroll
      for (int ni = 0; ni < NI; ++ni)
        acc[2 + mi][ni] = __builtin_amdgcn_mfma_f32_32x32x16_bf16(af[mi][s], bfr[ni][s],
                                                                  acc[2 + mi][ni], 0, 0, 0);
  __builtin_amdgcn_s_setprio(0);
}

// Grid: xcd = bid&7 (round-robin dispatch), lid = bid>>3; m = lid%MB, n = xcd*NPX+lid/MB.
template <int NI, int MB, int NPX, typename OutT>
__global__ __launch_bounds__(512, 2) void gemmQ(const __bf16* __restrict__ A,
                                                const __bf16* __restrict__ B,
                                                OutT* __restrict__ C, int K,
                                                int lda, int ldb, int ldc) {
  __shared__ __align__(16) __bf16 As[2][256 * 64];
  __shared__ __align__(16) __bf16 Bs[2][NI * 128 * 64];
  const int tid = threadIdx.x;
  const int lane = tid & 63, l31 = lane & 31, hi = lane >> 5, w = tid >> 6;
  const int wm = w >> 2, wn = w & 3;
  const int bid = blockIdx.x, xcd = bid & 7, lid = bid >> 3;
  const int m0 = (lid % MB) * 256;
  const int n0 = (xcd * NPX + lid / MB) * (NI * 128);

  f32x16 acc[4][NI] = {};
  bf16x8 bfr[NI][4];

  // prologue: tile 0 -> buf0 in FIFO order [A0,A0,B0,B1,(B2,B3),A1,A1]
  stg(A, lda, m0,       0, (char*)As[0],             tid);
  stg(A, lda, m0 + 128, 0, (char*)As[0] + 128 * 128, tid);
  stg(B, ldb, n0,       0, (char*)Bs[0],             tid);
  stg(B, ldb, n0 + 64,  0, (char*)Bs[0] + 64 * 128,  tid);
  if constexpr (NI == 2) {
    stg(B, ldb, n0 + 128, 0, (char*)Bs[0] + 128 * 128, tid);
    stg(B, ldb, n0 + 192, 0, (char*)Bs[0] + 192 * 128, tid);
  }
  stg(A, lda, m0 + 64,  0, (char*)As[0] + 64 * 128,  tid);
  stg(A, lda, m0 + 192, 0, (char*)As[0] + 192 * 128, tid);

  const int nt = K >> 6;
  for (int t = 0; t < nt; ++t) {
    const int cur = t & 1;
    const __bf16* Ab = As[cur];
    const __bf16* Bb = Bs[cur];
    char* dA = (char*)As[1 - cur];
    char* dB = (char*)Bs[1 - cur];
    if (t + 1 < nt) {
      phase0<NI, 2, true>(Ab, Bb, acc, bfr, wm, wn, l31, hi, tid, A, lda, m0, dA, B, ldb, n0, dB, t + 1);
      phase1<NI, 4, true>(Ab, acc, bfr, wm, l31, hi, tid, A, lda, m0, dA, B, ldb, n0, dB, t + 1);
    } else {
      phase0<NI, 2, false>(Ab, Bb, acc, bfr, wm, wn, l31, hi, tid, A, lda, m0, dA, B, ldb, n0, dB, 0);
      phase1<NI, 0, false>(Ab, acc, bfr, wm, l31, hi, tid, A, lda, m0, dA, B, ldb, n0, dB, 0);
    }
  }

  // epilogue: D col = l31 (n), row = (e&3) + 8*(e>>2) + 4*hi (m)
#pragma unroll
  for (int mi = 0; mi < 4; ++mi)
#pragma unroll
    for (int ni = 0; ni < NI; ++ni)
#pragma unroll
      for (int e = 0; e < 16; ++e) {
        int row = m0 + wm * 128 + mi * 32 + (e & 3) + 8 * (e >> 2) + 4 * hi;
        int col = n0 + wn * (NI * 32) + ni * 32 + l31;
        C[(size_t)row * ldc + col] = (OutT)acc[mi][ni][e];
      }
}

// ---------------- Flash attention, causal, GQA — staged K/V, 2 blocks/CU ---
// 512 blocks x 256 thr (4 waves x 32 q-rows, QBLK=128); one (head, q-tile)
// per block. qt = (g<8) ? 15-g : g-8 pairs block b with b+256 on the same CU
// slot -> per-CU work = 34 tiles (balanced), big jobs dispatch first (LPT).
__device__ inline uint32_t pack2(float a, float b) {
  bf16x2 t; t[0] = (__bf16)a; t[1] = (__bf16)b;
  return __builtin_bit_cast(uint32_t, t);
}

__global__ __launch_bounds__(256, 2) void attn_kernel(const __bf16* __restrict__ qkv,
                                                      __bf16* __restrict__ out) {
  __shared__ __align__(16) __bf16 Ks[2][64 * 128];   // XOR-swizzled 16B groups
  __shared__ __align__(16) __bf16 Vt[2][128][72];    // V^T, padded (stride 144B)
  const int tid = threadIdx.x;
  const int lane = tid & 63, l31 = lane & 31, hi = lane >> 5, wq = tid >> 6;
  const int head = blockIdx.x & 31;
  const int g = blockIdx.x >> 5;                     // 0..15
  const int qt = (g < 8) ? (15 - g) : (g - 8);       // LPT + slot pairing
  const int q0 = qt * 128;
  const int nt = 2 * qt + 2;                         // kv tiles (causal)
  const int kvh = head >> 2;
  const float sc2 = 0.08838834764831845f * 1.44269504089f;  // 1/sqrt(128)*log2(e)
  const int qr = q0 + wq * 32 + l31;                 // this lane's q row

  bf16x8 vr[2][2];  // in-flight V rows (2 tasks x 2 rows)

  auto stage_k = [&](int tt, int buf) {
#pragma unroll
    for (int i = 0; i < 4; ++i) {
      int c = i * 256 + tid;                         // 16B chunk 0..1023
      int r = c >> 4, gg = c & 15;
      const __bf16* gk = qkv + (size_t)(tt * 64 + r) * QKV_LD + KOFF + kvh * HD + ((gg ^ (r & 7)) * 8);
      __builtin_amdgcn_global_load_lds((gaddr_t)gk,
          (laddr_t)((char*)Ks[buf] + (tid & ~63) * 16 + i * 4096), 16, 0, 0);
    }
  };
  auto load_v = [&](int tt) {
#pragma unroll
    for (int i = 0; i < 2; ++i) {
      int task = i * 256 + tid;                      // 0..511
      int p = task >> 4, cg = task & 15;
      const __bf16* vp = qkv + (size_t)(tt * 64 + 2 * p) * QKV_LD + VOFF + kvh * HD + cg * 8;
      vr[i][0] = *reinterpret_cast<const bf16x8*>(vp);
      vr[i][1] = *reinterpret_cast<const bf16x8*>(vp + QKV_LD);
    }
  };
  auto write_v = [&](int buf) {
#pragma unroll
    for (int i = 0; i < 2; ++i) {
      int task = i * 256 + tid;
      int p = task >> 4, cg = task & 15;
#pragma unroll
      for (int e0 = 0; e0 < 8; ++e0) {
        int e = e0 ^ (lane & 7);
        bf16x2 pkv; pkv[0] = vr[i][0][e]; pkv[1] = vr[i][1][e];
        *reinterpret_cast<bf16x2*>(&Vt[buf][cg * 8 + e][2 * p]) = pkv;
      }
    }
  };

  // Q fragments (B-layout): lane holds Q[qr][k = ks*16 + hi*8 + 0..7]
  bf16x8 qf[8];
  {
    const __bf16* qp = qkv + (size_t)qr * QKV_LD + head * HD + hi * 8;
#pragma unroll
    for (int ks = 0; ks < 8; ++ks) qf[ks] = *reinterpret_cast<const bf16x8*>(qp + ks * 16);
  }
  f32x16 o[4] = {};
  float m_run = -3e38f, l_run = 0.f;

  stage_k(0, 0); load_v(0); write_v(0);

  for (int t = 0; t < nt; ++t) {
    const int cur = t & 1;
    __syncthreads();        // staging of buf[cur] visible; prev reads of buf[1-cur] done
    if (t + 1 < nt) { stage_k(t + 1, 1 - cur); load_v(t + 1); }

    // ---- S^T = K Q^T : col=q=l31, row=(e&3)+8*(e>>2)+4*hi
    f32x16 st[2];
#pragma unroll
    for (int sub = 0; sub < 2; ++sub) {
      f32x16 acc = {};
      int r = sub * 32 + l31;
#pragma unroll
      for (int ks = 0; ks < 8; ++ks) {
        int gg = (ks * 2 + hi) ^ (r & 7);
        bf16x8 kf = *reinterpret_cast<const bf16x8*>((char*)Ks[cur] + r * 256 + gg * 16);
        acc = __builtin_amdgcn_mfma_f32_32x32x16_bf16(kf, qf[ks], acc, 0, 0, 0);
      }
      st[sub] = acc;
    }
#pragma unroll
    for (int sub = 0; sub < 2; ++sub)
#pragma unroll
      for (int e = 0; e < 16; ++e) st[sub][e] *= sc2;
    if (t >= nt - 2) {      // only the two diagonal tiles need masking
      const int kv0 = t * 64;
#pragma unroll
      for (int sub = 0; sub < 2; ++sub)
#pragma unroll
        for (int e = 0; e < 16; ++e) {
          int kvg = kv0 + sub * 32 + (e & 3) + 8 * (e >> 2) + 4 * hi;
          if (kvg > qr) st[sub][e] = -1e30f;
        }
    }
    // ---- online softmax (lane-local, defer-max)
    float pm = st[0][0];
#pragma unroll
    for (int e = 1; e < 16; ++e) pm = fmaxf(pm, st[0][e]);
#pragma unroll
    for (int e = 0; e < 16; ++e) pm = fmaxf(pm, st[1][e]);
    pm = fmaxf(pm, __shfl_xor(pm, 32));
    if (!__all(pm - m_run <= 8.f)) {
      float mn = fmaxf(m_run, pm);
      float fsc = EXP2F(m_run - mn);
      m_run = mn;
      l_run *= fsc;
#pragma unroll
      for (int dt = 0; dt < 4; ++dt)
#pragma unroll
        for (int e = 0; e < 16; ++e) o[dt][e] *= fsc;
    }
    float rs = 0.f;
#pragma unroll
    for (int sub = 0; sub < 2; ++sub)
#pragma unroll
      for (int e = 0; e < 16; ++e) {
        float p = EXP2F(st[sub][e] - m_run);
        st[sub][e] = p;
        rs += p;
      }
    rs += __shfl_xor(rs, 32);
    l_run += rs;

    // ---- pack P to bf16 B-fragments: pf[tt] = P[qr][kv = tt*16 + hi*8 + 0..7]
    uint32_t pk[16];
#pragma unroll
    for (int sub = 0; sub < 2; ++sub)
#pragma unroll
      for (int i = 0; i < 8; ++i)
        pk[sub * 8 + i] = pack2(st[sub][2 * i], st[sub][2 * i + 1]);
    uint32_t rv[8];
#pragma unroll
    for (int m = 0; m < 8; ++m) {
      int base = 4 * (m >> 1) + (m & 1);
      uint32_t snd = hi ? pk[base] : pk[base + 2];
      rv[m] = __shfl_xor(snd, 32);
    }
    bf16x8 pf[4];
#pragma unroll
    for (int tt = 0; tt < 4; ++tt) {
      u32x4 wv;
      wv[0] = hi ? rv[2 * tt]     : pk[4 * tt];
      wv[1] = hi ? rv[2 * tt + 1] : pk[4 * tt + 1];
      wv[2] = hi ? pk[4 * tt + 2] : rv[2 * tt];
      wv[3] = hi ? pk[4 * tt + 3] : rv[2 * tt + 1];
      pf[tt] = __builtin_bit_cast(bf16x8, wv);
    }
    // ---- O^T += V^T P^T
#pragma unroll
    for (int dt = 0; dt < 4; ++dt) {
      int dr = dt * 32 + l31;
#pragma unroll
      for (int tt = 0; tt < 4; ++tt) {
        bf16x8 vf = *reinterpret_cast<const bf16x8*>((char*)&Vt[cur][0][0] + dr * 144 + tt * 32 + hi * 16);
        o[dt] = __builtin_amdgcn_mfma_f32_32x32x16_bf16(vf, pf[tt], o[dt], 0, 0, 0);
      }
    }
    // ---- late V^T write for next tile (loads had QK+softmax+PV to land)
    if (t + 1 < nt) write_v(1 - cur);
  }

  // ---- epilogue: transpose O^T -> O via per-wave LDS scratch, coalesced stores
  float inv = 1.f / l_run;
  __bf16* scr = &Ks[0][0] + wq * 1280;               // [32][40] bf16 per wave
  const int qq = lane >> 1, part = lane & 1;
#pragma unroll
  for (int dt = 0; dt < 4; ++dt) {
    __syncthreads();                                 // all waves done reading Ks/Vt (or prev dt)
#pragma unroll
    for (int i = 0; i < 8; ++i) {
      int d0 = (2 * i & 3) + 8 * (i >> 1) + 4 * hi;
      bf16x2 prr;
      prr[0] = (__bf16)(o[dt][2 * i] * inv);
      prr[1] = (__bf16)(o[dt][2 * i + 1] * inv);
      *reinterpret_cast<bf16x2*>(scr + l31 * 40 + d0) = prr;
    }
    __syncthreads();
    bf16x8 r0 = *reinterpret_cast<const bf16x8*>(scr + qq * 40 + part * 16);
    bf16x8 r1 = *reinterpret_cast<const bf16x8*>(scr + qq * 40 + part * 16 + 8);
    __bf16* op = out + (size_t)(q0 + wq * 32 + qq) * DIM_ + head * HD + dt * 32 + part * 16;
    *reinterpret_cast<bf16x8*>(op) = r0;
    *reinterpret_cast<bf16x8*>(op + 8) = r1;
  }
}

// ---------------------------------------------------------------------------
extern "C" void kernel_launch(void* const* d_in, const int* in_sizes, int n_in,
                              void* d_out, int out_size, void* d_ws, size_t ws_size,
                              hipStream_t stream) {
  (void)in_sizes; (void)n_in; (void)out_size; (void)ws_size;
  const float* x    = (const float*)d_in[0];
  const float* fc   = (const float*)d_in[1];
  const float* fs   = (const float*)d_in[2];
  // d_in[3] = mask (causal, hardcoded in attn_kernel)
  const float* wqkv = (const float*)d_in[4];
  const float* wo   = (const float*)d_in[5];
  float* out = (float*)d_out;

  char* ws = (char*)d_ws;
  __bf16* xb    = (__bf16*)(ws);                       // 16,777,216  (reused as attn_out)
  __bf16* wqkvb = (__bf16*)(ws + 16777216);            // 50,331,648
  __bf16* wob   = (__bf16*)(ws + 67108864);            // 33,554,432
  __bf16* qkv   = (__bf16*)(ws + 100663296);           // 25,165,824
  __bf16* attnO = xb;                                  // xb dead after gemm1

  cvt_f32_bf16<<<2048, 256, 0, stream>>>(x,    xb,    (S_LEN * DIM_) / 4);
  cvt_f32_bf16<<<2048, 256, 0, stream>>>(wqkv, wqkvb, (6144 * DIM_) / 4);
  cvt_f32_bf16<<<2048, 256, 0, stream>>>(wo,   wob,   (DIM_ * DIM_) / 4);

  // qkv = x @ wqkv^T : M=2048, N=6144, K=4096. 256x256 tiles -> 8x24 = 192 blocks.
  // Per-XCD chunk 8M x 3N.
  gemmQ<2, 8, 3, __bf16><<<192, 512, 0, stream>>>(xb, wqkvb, qkv, DIM_, DIM_, DIM_, QKV_LD);

  // rope on Q + K parts
  rope_kernel<<<(S_LEN * 40 * 64) / 256, 256, 0, stream>>>(qkv, fc, fs);

  // causal GQA attention (512 blocks x 256 threads, 2 blocks/CU, paired LPT)
  attn_kernel<<<512, 256, 0, stream>>>(qkv, attnO);

  // out = attnO @ wo^T : M=2048, N=4096, K=4096. 256x128 tiles -> 8x32 = 256 blocks.
  // Per-XCD chunk 8M x 4N.
  gemmQ<1, 8, 4, float><<<256, 512, 0, stream>>>(attnO, wob, out, DIM_, DIM_, DIM_, DIM_);
}

// Round 12
// 1322.031 us; speedup vs baseline: 1.0001x; 1.0001x over previous
//
#include <hip/hip_runtime.h>
#include <hip/hip_bf16.h>
#include <cstdint>
#include <cstddef>

// ---------------------------------------------------------------------------
// Attention block: qkv = x @ wqkv^T ; rope(q,k) ; causal GQA attention ; out = att @ wo^T
// B=1, S=2048, DIM=4096, NH=32, NKV=8, HD=128. All compute in bf16 MFMA + f32 accum.
// ---------------------------------------------------------------------------

typedef __attribute__((ext_vector_type(4)))  float    f32x4;
typedef __attribute__((ext_vector_type(16))) float    f32x16;
typedef __attribute__((ext_vector_type(8)))  __bf16   bf16x8;
typedef __attribute__((ext_vector_type(4)))  __bf16   bf16x4;
typedef __attribute__((ext_vector_type(2)))  __bf16   bf16x2;
typedef __attribute__((ext_vector_type(4)))  uint32_t u32x4;

typedef const __attribute__((address_space(1))) void* gaddr_t;
typedef __attribute__((address_space(3))) void*       laddr_t;

#define S_LEN   2048
#define DIM_    4096
#define NHEADS  32
#define NKV     8
#define HD      128
#define QKV_LD  6144   // row stride of qkv buffer (Q|K|V)
#define KOFF    4096
#define VOFF    5120

#define EXP2F(x) __builtin_amdgcn_exp2f(x)   // v_exp_f32 (2^x); __exp2f collides with glibc macro

// ---------------- f32 -> bf16 conversion (vectorized x4) -------------------
__global__ void cvt_f32_bf16(const float* __restrict__ in, __bf16* __restrict__ out, int n4) {
  int idx = blockIdx.x * blockDim.x + threadIdx.x;
  int stride = gridDim.x * blockDim.x;
  for (int i = idx; i < n4; i += stride) {
    float4 v = reinterpret_cast<const float4*>(in)[i];
    bf16x4 o;
    o[0] = (__bf16)v.x; o[1] = (__bf16)v.y; o[2] = (__bf16)v.z; o[3] = (__bf16)v.w;
    reinterpret_cast<bf16x4*>(out)[i] = o;
  }
}

// ---------------- RoPE in-place on Q and K parts of qkv --------------------
__global__ void rope_kernel(__bf16* __restrict__ qkv, const float* __restrict__ fc,
                            const float* __restrict__ fs) {
  int tid = blockIdx.x * 256 + threadIdx.x;   // 0 .. 2048*40*64-1
  int i = tid & 63;
  int t = tid >> 6;
  int h = t % 40;
  int s = t / 40;
  int col = (h < NHEADS) ? (h * HD + 2 * i) : (KOFF + (h - NHEADS) * HD + 2 * i);
  size_t off = (size_t)s * QKV_LD + col;
  float c = fc[s * 64 + i], sn = fs[s * 64 + i];
  bf16x2 v = *reinterpret_cast<bf16x2*>(&qkv[off]);
  float t0 = (float)v[0], t1 = (float)v[1];
  bf16x2 o;
  o[0] = (__bf16)(t0 * c - t1 * sn);
  o[1] = (__bf16)(t0 * sn + t1 * c);
  *reinterpret_cast<bf16x2*>(&qkv[off]) = o;
}

// ---------------- counted-vmcnt 32x32 GEMM: C = A[M,K] * B[N,K]^T ----------
// 512 thr = 8 waves (2M x 4N), BM=256, BN=NI*128, BK=64. Per-wave 128 x NI*32.
// B fragments read ONCE per K-tile (held in registers across both phases) ->
// per-wave LDS = 24KB/K-tile (structural minimum). Double-buffered LDS,
// half-tile staggered staging in FIFO [A0,A0,B0,B1,(B2,B3),A1,A1]; waits:
// phase0 vmcnt(2), phase1 vmcnt(4) steady / (2,0) last tile.
// NOTE: __launch_bounds__(512, 1) — the register footprint (acc 128 + bfr 32
// + af 32 + addr ~20 at NI=2) needs the full 256-VGPR budget; (512,2) caps at
// 128 VGPR and spills accumulators to scratch (R11: 2.9 GB WRITE, 7.7x slower).
template <int N> __device__ __forceinline__ void vmwait() {
  if constexpr (N == 0) asm volatile("s_waitcnt vmcnt(0)" ::: "memory");
  else if constexpr (N == 2) asm volatile("s_waitcnt vmcnt(2)" ::: "memory");
  else asm volatile("s_waitcnt vmcnt(4)" ::: "memory");
}

// one stage op: 64 rows x 128B (512 thr x 16B), linear LDS rows, swizzled src
__device__ __forceinline__ void stg(const __bf16* __restrict__ P, int ld, int grow0,
                                    int kt, char* dst, int tid) {
  int r = tid >> 3, g = tid & 7;
  int row = grow0 + r;
  const __bf16* src = P + (size_t)row * ld + kt * 64 + ((g ^ (row & 7)) * 8);
  __builtin_amdgcn_global_load_lds((gaddr_t)src,
      (laddr_t)(dst + (tid & ~63) * 16), 16, 0, 0);
}

template <int NI, int WAIT, bool ST>
__device__ __forceinline__ void phase0(const __bf16* __restrict__ Ab,
                                       const __bf16* __restrict__ Bb,
                                       f32x16 (&acc)[4][NI], bf16x8 (&bfr)[NI][4],
                                       int wm, int wn, int l31, int hi, int tid,
                                       const __bf16* __restrict__ A, int lda, int m0, char* dA,
                                       const __bf16* __restrict__ B, int ldb, int n0, char* dB,
                                       int kt) {
  vmwait<WAIT>();
  __builtin_amdgcn_s_barrier();
  bf16x8 af[2][4];
#pragma unroll
  for (int mi = 0; mi < 2; ++mi) {
    int R = wm * 128 + mi * 32 + l31;                 // A-half0 rows
#pragma unroll
    for (int s = 0; s < 4; ++s)
      af[mi][s] = *reinterpret_cast<const bf16x8*>(
          (const char*)Ab + R * 128 + (((s * 2 + hi) ^ (R & 7)) * 16));
  }
#pragma unroll
  for (int ni = 0; ni < NI; ++ni) {                   // ALL B frags (held for phase1)
    int R = wn * (NI * 32) + ni * 32 + l31;
#pragma unroll
    for (int s = 0; s < 4; ++s)
      bfr[ni][s] = *reinterpret_cast<const bf16x8*>(
          (const char*)Bb + R * 128 + (((s * 2 + hi) ^ (R & 7)) * 16));
  }
  if constexpr (ST) {                                 // FIFO: A0,A0,B0,B1
    stg(A, lda, m0,       kt, dA,             tid);
    stg(A, lda, m0 + 128, kt, dA + 128 * 128, tid);
    stg(B, ldb, n0,       kt, dB,             tid);
    stg(B, ldb, n0 + 64,  kt, dB + 64 * 128,  tid);
  }
  asm volatile("s_waitcnt lgkmcnt(0)" ::: "memory");
  __builtin_amdgcn_sched_barrier(0);
  __builtin_amdgcn_s_setprio(1);
#pragma unroll
  for (int s = 0; s < 4; ++s)
#pragma unroll
    for (int mi = 0; mi < 2; ++mi)
#pragma unroll
      for (int ni = 0; ni < NI; ++ni)
        acc[mi][ni] = __builtin_amdgcn_mfma_f32_32x32x16_bf16(af[mi][s], bfr[ni][s],
                                                              acc[mi][ni], 0, 0, 0);
  __builtin_amdgcn_s_setprio(0);
}

template <int NI, int WAIT, bool ST>
__device__ __forceinline__ void phase1(const __bf16* __restrict__ Ab,
                                       f32x16 (&acc)[4][NI], bf16x8 (&bfr)[NI][4],
                                       int wm, int l31, int hi, int tid,
                                       const __bf16* __restrict__ A, int lda, int m0, char* dA,
                                       const __bf16* __restrict__ B, int ldb, int n0, char* dB,
                                       int kt) {
  vmwait<WAIT>();
  __builtin_amdgcn_s_barrier();
  bf16x8 af[2][4];
#pragma unroll
  for (int mi = 0; mi < 2; ++mi) {
    int R = wm * 128 + 64 + mi * 32 + l31;            // A-half1 rows
#pragma unroll
    for (int s = 0; s < 4; ++s)
      af[mi][s] = *reinterpret_cast<const bf16x8*>(
          (const char*)Ab + R * 128 + (((s * 2 + hi) ^ (R & 7)) * 16));
  }
  if constexpr (ST) {                                 // FIFO: (B2,B3),A1,A1
    if constexpr (NI == 2) {
      stg(B, ldb, n0 + 128, kt, dB + 128 * 128, tid);
      stg(B, ldb, n0 + 192, kt, dB + 192 * 128, tid);
    }
    stg(A, lda, m0 + 64,  kt, dA + 64 * 128,  tid);
    stg(A, lda, m0 + 192, kt, dA + 192 * 128, tid);
  }
  asm volatile("s_waitcnt lgkmcnt(0)" ::: "memory");
  __builtin_amdgcn_sched_barrier(0);
  __builtin_amdgcn_s_setprio(1);
#pragma unroll
  for (int s = 0; s < 4; ++s)
#pragma unroll
    for (int mi = 0; mi < 2; ++mi)
#pragma unroll
      for (int ni = 0; ni < NI; ++ni)
        acc[2 + mi][ni] = __builtin_amdgcn_mfma_f32_32x32x16_bf16(af[mi][s], bfr[ni][s],
                                                                  acc[2 + mi][ni], 0, 0, 0);
  __builtin_amdgcn_s_setprio(0);
}

// Grid: xcd = bid&7 (round-robin dispatch), lid = bid>>3; m = lid%MB, n = xcd*NPX+lid/MB.
template <int NI, int MB, int NPX, typename OutT>
__global__ __launch_bounds__(512, 1) void gemmQ(const __bf16* __restrict__ A,
                                                const __bf16* __restrict__ B,
                                                OutT* __restrict__ C, int K,
                                                int lda, int ldb, int ldc) {
  __shared__ __align__(16) __bf16 As[2][256 * 64];
  __shared__ __align__(16) __bf16 Bs[2][NI * 128 * 64];
  const int tid = threadIdx.x;
  const int lane = tid & 63, l31 = lane & 31, hi = lane >> 5, w = tid >> 6;
  const int wm = w >> 2, wn = w & 3;
  const int bid = blockIdx.x, xcd = bid & 7, lid = bid >> 3;
  const int m0 = (lid % MB) * 256;
  const int n0 = (xcd * NPX + lid / MB) * (NI * 128);

  f32x16 acc[4][NI] = {};
  bf16x8 bfr[NI][4];

  // prologue: tile 0 -> buf0 in FIFO order [A0,A0,B0,B1,(B2,B3),A1,A1]
  stg(A, lda, m0,       0, (char*)As[0],             tid);
  stg(A, lda, m0 + 128, 0, (char*)As[0] + 128 * 128, tid);
  stg(B, ldb, n0,       0, (char*)Bs[0],             tid);
  stg(B, ldb, n0 + 64,  0, (char*)Bs[0] + 64 * 128,  tid);
  if constexpr (NI == 2) {
    stg(B, ldb, n0 + 128, 0, (char*)Bs[0] + 128 * 128, tid);
    stg(B, ldb, n0 + 192, 0, (char*)Bs[0] + 192 * 128, tid);
  }
  stg(A, lda, m0 + 64,  0, (char*)As[0] + 64 * 128,  tid);
  stg(A, lda, m0 + 192, 0, (char*)As[0] + 192 * 128, tid);

  const int nt = K >> 6;
  for (int t = 0; t < nt; ++t) {
    const int cur = t & 1;
    const __bf16* Ab = As[cur];
    const __bf16* Bb = Bs[cur];
    char* dA = (char*)As[1 - cur];
    char* dB = (char*)Bs[1 - cur];
    if (t + 1 < nt) {
      phase0<NI, 2, true>(Ab, Bb, acc, bfr, wm, wn, l31, hi, tid, A, lda, m0, dA, B, ldb, n0, dB, t + 1);
      phase1<NI, 4, true>(Ab, acc, bfr, wm, l31, hi, tid, A, lda, m0, dA, B, ldb, n0, dB, t + 1);
    } else {
      phase0<NI, 2, false>(Ab, Bb, acc, bfr, wm, wn, l31, hi, tid, A, lda, m0, dA, B, ldb, n0, dB, 0);
      phase1<NI, 0, false>(Ab, acc, bfr, wm, l31, hi, tid, A, lda, m0, dA, B, ldb, n0, dB, 0);
    }
  }

  // epilogue: D col = l31 (n), row = (e&3) + 8*(e>>2) + 4*hi (m)
#pragma unroll
  for (int mi = 0; mi < 4; ++mi)
#pragma unroll
    for (int ni = 0; ni < NI; ++ni)
#pragma unroll
      for (int e = 0; e < 16; ++e) {
        int row = m0 + wm * 128 + mi * 32 + (e & 3) + 8 * (e >> 2) + 4 * hi;
        int col = n0 + wn * (NI * 32) + ni * 32 + l31;
        C[(size_t)row * ldc + col] = (OutT)acc[mi][ni][e];
      }
}

// ---------------- Flash attention, causal, GQA — staged K/V, 2 blocks/CU ---
// 512 blocks x 256 thr (4 waves x 32 q-rows, QBLK=128); one (head, q-tile)
// per block. qt = (g<8) ? 15-g : g-8 pairs block b with b+256 on the same CU
// slot -> per-CU work = 34 tiles (balanced), big jobs dispatch first (LPT).
__device__ inline uint32_t pack2(float a, float b) {
  bf16x2 t; t[0] = (__bf16)a; t[1] = (__bf16)b;
  return __builtin_bit_cast(uint32_t, t);
}

__global__ __launch_bounds__(256, 2) void attn_kernel(const __bf16* __restrict__ qkv,
                                                      __bf16* __restrict__ out) {
  __shared__ __align__(16) __bf16 Ks[2][64 * 128];   // XOR-swizzled 16B groups
  __shared__ __align__(16) __bf16 Vt[2][128][72];    // V^T, padded (stride 144B)
  const int tid = threadIdx.x;
  const int lane = tid & 63, l31 = lane & 31, hi = lane >> 5, wq = tid >> 6;
  const int head = blockIdx.x & 31;
  const int g = blockIdx.x >> 5;                     // 0..15
  const int qt = (g < 8) ? (15 - g) : (g - 8);       // LPT + slot pairing
  const int q0 = qt * 128;
  const int nt = 2 * qt + 2;                         // kv tiles (causal)
  const int kvh = head >> 2;
  const float sc2 = 0.08838834764831845f * 1.44269504089f;  // 1/sqrt(128)*log2(e)
  const int qr = q0 + wq * 32 + l31;                 // this lane's q row

  bf16x8 vr[2][2];  // in-flight V rows (2 tasks x 2 rows)

  auto stage_k = [&](int tt, int buf) {
#pragma unroll
    for (int i = 0; i < 4; ++i) {
      int c = i * 256 + tid;                         // 16B chunk 0..1023
      int r = c >> 4, gg = c & 15;
      const __bf16* gk = qkv + (size_t)(tt * 64 + r) * QKV_LD + KOFF + kvh * HD + ((gg ^ (r & 7)) * 8);
      __builtin_amdgcn_global_load_lds((gaddr_t)gk,
          (laddr_t)((char*)Ks[buf] + (tid & ~63) * 16 + i * 4096), 16, 0, 0);
    }
  };
  auto load_v = [&](int tt) {
#pragma unroll
    for (int i = 0; i < 2; ++i) {
      int task = i * 256 + tid;                      // 0..511
      int p = task >> 4, cg = task & 15;
      const __bf16* vp = qkv + (size_t)(tt * 64 + 2 * p) * QKV_LD + VOFF + kvh * HD + cg * 8;
      vr[i][0] = *reinterpret_cast<const bf16x8*>(vp);
      vr[i][1] = *reinterpret_cast<const bf16x8*>(vp + QKV_LD);
    }
  };
  auto write_v = [&](int buf) {
#pragma unroll
    for (int i = 0; i < 2; ++i) {
      int task = i * 256 + tid;
      int p = task >> 4, cg = task & 15;
#pragma unroll
      for (int e0 = 0; e0 < 8; ++e0) {
        int e = e0 ^ (lane & 7);
        bf16x2 pkv; pkv[0] = vr[i][0][e]; pkv[1] = vr[i][1][e];
        *reinterpret_cast<bf16x2*>(&Vt[buf][cg * 8 + e][2 * p]) = pkv;
      }
    }
  };

  // Q fragments (B-layout): lane holds Q[qr][k = ks*16 + hi*8 + 0..7]
  bf16x8 qf[8];
  {
    const __bf16* qp = qkv + (size_t)qr * QKV_LD + head * HD + hi * 8;
#pragma unroll
    for (int ks = 0; ks < 8; ++ks) qf[ks] = *reinterpret_cast<const bf16x8*>(qp + ks * 16);
  }
  f32x16 o[4] = {};
  float m_run = -3e38f, l_run = 0.f;

  stage_k(0, 0); load_v(0); write_v(0);

  for (int t = 0; t < nt; ++t) {
    const int cur = t & 1;
    __syncthreads();        // staging of buf[cur] visible; prev reads of buf[1-cur] done
    if (t + 1 < nt) { stage_k(t + 1, 1 - cur); load_v(t + 1); }

    // ---- S^T = K Q^T : col=q=l31, row=(e&3)+8*(e>>2)+4*hi
    f32x16 st[2];
#pragma unroll
    for (int sub = 0; sub < 2; ++sub) {
      f32x16 acc = {};
      int r = sub * 32 + l31;
#pragma unroll
      for (int ks = 0; ks < 8; ++ks) {
        int gg = (ks * 2 + hi) ^ (r & 7);
        bf16x8 kf = *reinterpret_cast<const bf16x8*>((char*)Ks[cur] + r * 256 + gg * 16);
        acc = __builtin_amdgcn_mfma_f32_32x32x16_bf16(kf, qf[ks], acc, 0, 0, 0);
      }
      st[sub] = acc;
    }
#pragma unroll
    for (int sub = 0; sub < 2; ++sub)
#pragma unroll
      for (int e = 0; e < 16; ++e) st[sub][e] *= sc2;
    if (t >= nt - 2) {      // only the two diagonal tiles need masking
      const int kv0 = t * 64;
#pragma unroll
      for (int sub = 0; sub < 2; ++sub)
#pragma unroll
        for (int e = 0; e < 16; ++e) {
          int kvg = kv0 + sub * 32 + (e & 3) + 8 * (e >> 2) + 4 * hi;
          if (kvg > qr) st[sub][e] = -1e30f;
        }
    }
    // ---- online softmax (lane-local, defer-max)
    float pm = st[0][0];
#pragma unroll
    for (int e = 1; e < 16; ++e) pm = fmaxf(pm, st[0][e]);
#pragma unroll
    for (int e = 0; e < 16; ++e) pm = fmaxf(pm, st[1][e]);
    pm = fmaxf(pm, __shfl_xor(pm, 32));
    if (!__all(pm - m_run <= 8.f)) {
      float mn = fmaxf(m_run, pm);
      float fsc = EXP2F(m_run - mn);
      m_run = mn;
      l_run *= fsc;
#pragma unroll
      for (int dt = 0; dt < 4; ++dt)
#pragma unroll
        for (int e = 0; e < 16; ++e) o[dt][e] *= fsc;
    }
    float rs = 0.f;
#pragma unroll
    for (int sub = 0; sub < 2; ++sub)
#pragma unroll
      for (int e = 0; e < 16; ++e) {
        float p = EXP2F(st[sub][e] - m_run);
        st[sub][e] = p;
        rs += p;
      }
    rs += __shfl_xor(rs, 32);
    l_run += rs;

    // ---- pack P to bf16 B-fragments: pf[tt] = P[qr][kv = tt*16 + hi*8 + 0..7]
    uint32_t pk[16];
#pragma unroll
    for (int sub = 0; sub < 2; ++sub)
#pragma unroll
      for (int i = 0; i < 8; ++i)
        pk[sub * 8 + i] = pack2(st[sub][2 * i], st[sub][2 * i + 1]);
    uint32_t rv[8];
#pragma unroll
    for (int m = 0; m < 8; ++m) {
      int base = 4 * (m >> 1) + (m & 1);
      uint32_t snd = hi ? pk[base] : pk[base + 2];
      rv[m] = __shfl_xor(snd, 32);
    }
    bf16x8 pf[4];
#pragma unroll
    for (int tt = 0; tt < 4; ++tt) {
      u32x4 wv;
      wv[0] = hi ? rv[2 * tt]     : pk[4 * tt];
      wv[1] = hi ? rv[2 * tt + 1] : pk[4 * tt + 1];
      wv[2] = hi ? pk[4 * tt + 2] : rv[2 * tt];
      wv[3] = hi ? pk[4 * tt + 3] : rv[2 * tt + 1];
      pf[tt] = __builtin_bit_cast(bf16x8, wv);
    }
    // ---- O^T += V^T P^T
#pragma unroll
    for (int dt = 0; dt < 4; ++dt) {
      int dr = dt * 32 + l31;
#pragma unroll
      for (int tt = 0; tt < 4; ++tt) {
        bf16x8 vf = *reinterpret_cast<const bf16x8*>((char*)&Vt[cur][0][0] + dr * 144 + tt * 32 + hi * 16);
        o[dt] = __builtin_amdgcn_mfma_f32_32x32x16_bf16(vf, pf[tt], o[dt], 0, 0, 0);
      }
    }
    // ---- late V^T write for next tile (loads had QK+softmax+PV to land)
    if (t + 1 < nt) write_v(1 - cur);
  }

  // ---- epilogue: transpose O^T -> O via per-wave LDS scratch, coalesced stores
  float inv = 1.f / l_run;
  __bf16* scr = &Ks[0][0] + wq * 1280;               // [32][40] bf16 per wave
  const int qq = lane >> 1, part = lane & 1;
#pragma unroll
  for (int dt = 0; dt < 4; ++dt) {
    __syncthreads();                                 // all waves done reading Ks/Vt (or prev dt)
#pragma unroll
    for (int i = 0; i < 8; ++i) {
      int d0 = (2 * i & 3) + 8 * (i >> 1) + 4 * hi;
      bf16x2 prr;
      prr[0] = (__bf16)(o[dt][2 * i] * inv);
      prr[1] = (__bf16)(o[dt][2 * i + 1] * inv);
      *reinterpret_cast<bf16x2*>(scr + l31 * 40 + d0) = prr;
    }
    __syncthreads();
    bf16x8 r0 = *reinterpret_cast<const bf16x8*>(scr + qq * 40 + part * 16);
    bf16x8 r1 = *reinterpret_cast<const bf16x8*>(scr + qq * 40 + part * 16 + 8);
    __bf16* op = out + (size_t)(q0 + wq * 32 + qq) * DIM_ + head * HD + dt * 32 + part * 16;
    *reinterpret_cast<bf16x8*>(op) = r0;
    *reinterpret_cast<bf16x8*>(op + 8) = r1;
  }
}

// ---------------------------------------------------------------------------
extern "C" void kernel_launch(void* const* d_in, const int* in_sizes, int n_in,
                              void* d_out, int out_size, void* d_ws, size_t ws_size,
                              hipStream_t stream) {
  (void)in_sizes; (void)n_in; (void)out_size; (void)ws_size;
  const float* x    = (const float*)d_in[0];
  const float* fc   = (const float*)d_in[1];
  const float* fs   = (const float*)d_in[2];
  // d_in[3] = mask (causal, hardcoded in attn_kernel)
  const float* wqkv = (const float*)d_in[4];
  const float* wo   = (const float*)d_in[5];
  float* out = (float*)d_out;

  char* ws = (char*)d_ws;
  __bf16* xb    = (__bf16*)(ws);                       // 16,777,216  (reused as attn_out)
  __bf16* wqkvb = (__bf16*)(ws + 16777216);            // 50,331,648
  __bf16* wob   = (__bf16*)(ws + 67108864);            // 33,554,432
  __bf16* qkv   = (__bf16*)(ws + 100663296);           // 25,165,824
  __bf16* attnO = xb;                                  // xb dead after gemm1

  cvt_f32_bf16<<<2048, 256, 0, stream>>>(x,    xb,    (S_LEN * DIM_) / 4);
  cvt_f32_bf16<<<2048, 256, 0, stream>>>(wqkv, wqkvb, (6144 * DIM_) / 4);
  cvt_f32_bf16<<<2048, 256, 0, stream>>>(wo,   wob,   (DIM_ * DIM_) / 4);

  // qkv = x @ wqkv^T : M=2048, N=6144, K=4096. 256x256 tiles -> 8x24 = 192 blocks.
  // Per-XCD chunk 8M x 3N.
  gemmQ<2, 8, 3, __bf16><<<192, 512, 0, stream>>>(xb, wqkvb, qkv, DIM_, DIM_, DIM_, QKV_LD);

  // rope on Q + K parts
  rope_kernel<<<(S_LEN * 40 * 64) / 256, 256, 0, stream>>>(qkv, fc, fs);

  // causal GQA attention (512 blocks x 256 threads, 2 blocks/CU, paired LPT)
  attn_kernel<<<512, 256, 0, stream>>>(qkv, attnO);

  // out = attnO @ wo^T : M=2048, N=4096, K=4096. 256x128 tiles -> 8x32 = 256 blocks.
  // Per-XCD chunk 8M x 4N.
  gemmQ<1, 8, 4, float><<<256, 512, 0, stream>>>(attnO, wob, out, DIM_, DIM_, DIM_, DIM_);
}

// Round 13
// 388.345 us; speedup vs baseline: 3.4047x; 3.4043x over previous
//
#include <hip/hip_runtime.h>
#include <hip/hip_bf16.h>
#include <cstdint>
#include <cstddef>

// ---------------------------------------------------------------------------
// Attention block: qkv = x @ wqkv^T ; rope(q,k) ; causal GQA attention ; out = att @ wo^T
// B=1, S=2048, DIM=4096, NH=32, NKV=8, HD=128. All compute in bf16 MFMA + f32 accum.
// ---------------------------------------------------------------------------

typedef __attribute__((ext_vector_type(4)))  float    f32x4;
typedef __attribute__((ext_vector_type(16))) float    f32x16;
typedef __attribute__((ext_vector_type(8)))  __bf16   bf16x8;
typedef __attribute__((ext_vector_type(4)))  __bf16   bf16x4;
typedef __attribute__((ext_vector_type(2)))  __bf16   bf16x2;
typedef __attribute__((ext_vector_type(4)))  uint32_t u32x4;

typedef const __attribute__((address_space(1))) void* gaddr_t;
typedef __attribute__((address_space(3))) void*       laddr_t;

#define S_LEN   2048
#define DIM_    4096
#define NHEADS  32
#define NKV     8
#define HD      128
#define QKV_LD  6144   // row stride of qkv buffer (Q|K|V)
#define KOFF    4096
#define VOFF    5120

#define EXP2F(x) __builtin_amdgcn_exp2f(x)   // v_exp_f32 (2^x); __exp2f collides with glibc macro

// ---------------- f32 -> bf16 conversion (vectorized x4) -------------------
__global__ void cvt_f32_bf16(const float* __restrict__ in, __bf16* __restrict__ out, int n4) {
  int idx = blockIdx.x * blockDim.x + threadIdx.x;
  int stride = gridDim.x * blockDim.x;
  for (int i = idx; i < n4; i += stride) {
    float4 v = reinterpret_cast<const float4*>(in)[i];
    bf16x4 o;
    o[0] = (__bf16)v.x; o[1] = (__bf16)v.y; o[2] = (__bf16)v.z; o[3] = (__bf16)v.w;
    reinterpret_cast<bf16x4*>(out)[i] = o;
  }
}

// ---------------- RoPE in-place on Q and K parts of qkv --------------------
__global__ void rope_kernel(__bf16* __restrict__ qkv, const float* __restrict__ fc,
                            const float* __restrict__ fs) {
  int tid = blockIdx.x * 256 + threadIdx.x;   // 0 .. 2048*40*64-1
  int i = tid & 63;
  int t = tid >> 6;
  int h = t % 40;
  int s = t / 40;
  int col = (h < NHEADS) ? (h * HD + 2 * i) : (KOFF + (h - NHEADS) * HD + 2 * i);
  size_t off = (size_t)s * QKV_LD + col;
  float c = fc[s * 64 + i], sn = fs[s * 64 + i];
  bf16x2 v = *reinterpret_cast<bf16x2*>(&qkv[off]);
  float t0 = (float)v[0], t1 = (float)v[1];
  bf16x2 o;
  o[0] = (__bf16)(t0 * c - t1 * sn);
  o[1] = (__bf16)(t0 * sn + t1 * c);
  *reinterpret_cast<bf16x2*>(&qkv[off]) = o;
}

// ---------------- m201-style 8-phase GEMM: C = A[M,K] * B[N,K]^T -----------
// 512 thr = 8 waves (2M x 4N), BK=64, 16x16x32 MFMA (l15-row frags, 0-conflict
// swizzle). Quadrant phases (QM,QN): each A/B HALF is read only in its 2
// phases -> halves retire early; each phase stages exactly ONE half-tile into
// the slot freed one phase prior. Counted vmcnt (never 0 in loop):
//   W1 = 2a+2b at phases 4/8-end, W2 = 2a+b at phases 1/5-end
// (a,b = gloads per A/B half). Every drained load has >=3 phases (~900cy)
// cover. Prologue stages 6 half-tiles, waits vmcnt(a+b).
template <int N> __device__ __forceinline__ void vmw() {
  if constexpr (N == 3)      asm volatile("s_waitcnt vmcnt(3)" ::: "memory");
  else if constexpr (N == 4) asm volatile("s_waitcnt vmcnt(4)" ::: "memory");
  else if constexpr (N == 6) asm volatile("s_waitcnt vmcnt(6)" ::: "memory");
  else if constexpr (N == 8) asm volatile("s_waitcnt vmcnt(8)" ::: "memory");
  else if constexpr (N == 0) asm volatile("s_waitcnt vmcnt(0)" ::: "memory");
}

// one stage op: 64 rows x 128B (512 thr x 16B), linear LDS rows, inverse-
// swizzled global source (read side XORs the same involution)
__device__ __forceinline__ void stg64(const __bf16* __restrict__ P, int ld, int grow0,
                                      int kt, char* dst, int tid) {
  int r = tid >> 3, g = tid & 7;
  int row = grow0 + r;
  const __bf16* src = P + (size_t)row * ld + kt * 64 + ((g ^ (row & 7)) * 8);
  __builtin_amdgcn_global_load_lds((gaddr_t)src,
      (laddr_t)(dst + (tid & ~63) * 16), 16, 0, 0);
}

// stage one half-tile (NR64 x 64-row chunks)
template <int NR64>
__device__ __forceinline__ void stg_half(const __bf16* __restrict__ P, int ld, int grow0,
                                         int kt, char* dst, int tid) {
#pragma unroll
  for (int h = 0; h < NR64; ++h) stg64(P, ld, grow0 + h * 64, kt, dst + h * 8192, tid);
}

// One phase: quadrant (QM,QN) of the K-tile in (Ab,Bb); optionally stage one
// half-tile; VW >= 0 inserts the counted vmcnt before the trailing barrier.
template <int BM, int BN, int QM, int QN, int VW, int SNR>
__device__ __forceinline__ void do_phase(const __bf16* __restrict__ Ab,
                                         const __bf16* __restrict__ Bb,
                                         f32x4 (&acc)[2 * (BM / 64)][2 * (BN / 128)],
                                         int wm, int wn, int l15, int hi, int tid,
                                         const __bf16* __restrict__ SP, int sld,
                                         int sgrow0, int skt, char* sdst, bool doSt) {
  constexpr int FM2 = BM / 64;    // A frags per quadrant per wave
  constexpr int FN2 = BN / 128;   // B frags per quadrant per wave
  bf16x8 af[FM2][2], bf[FN2][2];
#pragma unroll
  for (int fm = 0; fm < FM2; ++fm) {
    int R = QM * (BM / 2) + wm * (BM / 4) + fm * 16 + l15;
#pragma unroll
    for (int kk = 0; kk < 2; ++kk)
      af[fm][kk] = *reinterpret_cast<const bf16x8*>(
          (const char*)Ab + R * 128 + (((kk * 4 + hi) ^ (R & 7)) * 16));
  }
#pragma unroll
  for (int fn = 0; fn < FN2; ++fn) {
    int R = QN * (BN / 2) + wn * (BN / 8) + fn * 16 + l15;
#pragma unroll
    for (int kk = 0; kk < 2; ++kk)
      bf[fn][kk] = *reinterpret_cast<const bf16x8*>(
          (const char*)Bb + R * 128 + (((kk * 4 + hi) ^ (R & 7)) * 16));
  }
  if (doSt) stg_half<SNR>(SP, sld, sgrow0, skt, sdst, tid);
  __builtin_amdgcn_s_barrier();
  asm volatile("s_waitcnt lgkmcnt(0)" ::: "memory");
  __builtin_amdgcn_sched_barrier(0);
  __builtin_amdgcn_s_setprio(1);
#pragma unroll
  for (int kk = 0; kk < 2; ++kk)
#pragma unroll
    for (int fm = 0; fm < FM2; ++fm)
#pragma unroll
      for (int fn = 0; fn < FN2; ++fn)
        acc[QM * FM2 + fm][QN * FN2 + fn] = __builtin_amdgcn_mfma_f32_16x16x32_bf16(
            af[fm][kk], bf[fn][kk], acc[QM * FM2 + fm][QN * FN2 + fn], 0, 0, 0);
  __builtin_amdgcn_s_setprio(0);
  if constexpr (VW >= 0) vmw<VW>();
  __builtin_amdgcn_s_barrier();
}

// Grid: xcd = bid&7 (round-robin dispatch), lid = bid>>3; m = lid%MB, n = xcd*NX + lid/MB.
template <int BM, int BN, int MB, int NX, typename OutT>
__global__ __launch_bounds__(512) void gemm8p(const __bf16* __restrict__ A,
                                              const __bf16* __restrict__ B,
                                              OutT* __restrict__ C, int K,
                                              int lda, int ldb, int ldc) {
  constexpr int AH = BM / 128;            // gloads per A half-tile
  constexpr int BH = BN / 128;            // gloads per B half-tile
  constexpr int W0 = AH + BH;             // prologue wait
  constexpr int W1 = 2 * AH + 2 * BH;     // phases 4/8
  constexpr int W2 = 2 * AH + BH;         // phases 1/5
  constexpr int FM2 = BM / 64, FN2 = BN / 128;
  __shared__ __align__(16) __bf16 As[2][BM * 64];
  __shared__ __align__(16) __bf16 Bs[2][BN * 64];
  const int tid = threadIdx.x;
  const int l15 = tid & 15, hi = (tid >> 4) & 3, w = tid >> 6;
  const int wm = w >> 2, wn = w & 3;
  const int bid = blockIdx.x, xcd = bid & 7, lid = bid >> 3;
  const int m0 = (lid % MB) * BM;
  const int n0 = (xcd * NX + lid / MB) * BN;

  f32x4 acc[2 * FM2][2 * FN2] = {};

  char* A0 = (char*)As[0]; char* A1 = (char*)As[1];
  char* B0 = (char*)Bs[0]; char* B1 = (char*)Bs[1];
  const int Ah = (BM / 2) * 128;          // byte offset of A half1
  const int Bh = (BN / 2) * 128;

  // prologue: t0 {A0,B0,A1,B1} -> buf0 ; t1 {A0,B0} -> buf1 (FIFO order)
  stg_half<AH>(A, lda, m0,          0, A0,      tid);
  stg_half<BH>(B, ldb, n0,          0, B0,      tid);
  stg_half<AH>(A, lda, m0 + BM / 2, 0, A0 + Ah, tid);
  stg_half<BH>(B, ldb, n0 + BN / 2, 0, B0 + Bh, tid);
  stg_half<AH>(A, lda, m0,          1, A1,      tid);
  stg_half<BH>(B, ldb, n0,          1, B1,      tid);
  vmw<W0>();
  __builtin_amdgcn_s_barrier();

  const int nt = K >> 6;                  // 64-wide K-tiles (even)
  for (int it = 0; it < nt; it += 2) {
    const bool s2 = (it + 2 < nt), s3 = (it + 3 < nt);
    // phases 1-4: consume buf0 (tile it)
    do_phase<BM, BN, 0, 0, W2, AH>(As[0], Bs[0], acc, wm, wn, l15, hi, tid,
                                   A, lda, m0 + BM / 2, it + 1, A1 + Ah, true);
    do_phase<BM, BN, 0, 1, -1, BH>(As[0], Bs[0], acc, wm, wn, l15, hi, tid,
                                   B, ldb, n0 + BN / 2, it + 1, B1 + Bh, true);
    do_phase<BM, BN, 1, 0, -1, AH>(As[0], Bs[0], acc, wm, wn, l15, hi, tid,
                                   A, lda, m0, it + 2, A0, s2);
    do_phase<BM, BN, 1, 1, W1, BH>(As[0], Bs[0], acc, wm, wn, l15, hi, tid,
                                   B, ldb, n0, it + 2, B0, s2);
    // phases 5-8: consume buf1 (tile it+1)
    do_phase<BM, BN, 0, 0, W2, AH>(As[1], Bs[1], acc, wm, wn, l15, hi, tid,
                                   A, lda, m0 + BM / 2, it + 2, A0 + Ah, s2);
    do_phase<BM, BN, 0, 1, -1, BH>(As[1], Bs[1], acc, wm, wn, l15, hi, tid,
                                   B, ldb, n0 + BN / 2, it + 2, B0 + Bh, s2);
    do_phase<BM, BN, 1, 0, -1, AH>(As[1], Bs[1], acc, wm, wn, l15, hi, tid,
                                   A, lda, m0, it + 3, A1, s3);
    do_phase<BM, BN, 1, 1, W1, BH>(As[1], Bs[1], acc, wm, wn, l15, hi, tid,
                                   B, ldb, n0, it + 3, B1, s3);
  }

  // epilogue: C row = qm*(BM/2)+wm*(BM/4)+fm*16+hi*4+j, col = qn*(BN/2)+wn*(BN/8)+fn*16+l15
#pragma unroll
  for (int qm = 0; qm < 2; ++qm)
#pragma unroll
    for (int fm = 0; fm < FM2; ++fm)
#pragma unroll
      for (int qn = 0; qn < 2; ++qn)
#pragma unroll
        for (int fn = 0; fn < FN2; ++fn)
#pragma unroll
          for (int j = 0; j < 4; ++j) {
            int row = m0 + qm * (BM / 2) + wm * (BM / 4) + fm * 16 + hi * 4 + j;
            int col = n0 + qn * (BN / 2) + wn * (BN / 8) + fn * 16 + l15;
            C[(size_t)row * ldc + col] = (OutT)acc[qm * FM2 + fm][qn * FN2 + fn][j];
          }
}

// ---------------- Flash attention, causal, GQA — staged K/V, 2 blocks/CU ---
// 512 blocks x 256 thr (4 waves x 32 q-rows, QBLK=128); one (head, q-tile)
// per block. qt = (g<8) ? 15-g : g-8 pairs block b with b+256 on the same CU
// slot -> per-CU work = 34 tiles (balanced), big jobs dispatch first (LPT).
__device__ inline uint32_t pack2(float a, float b) {
  bf16x2 t; t[0] = (__bf16)a; t[1] = (__bf16)b;
  return __builtin_bit_cast(uint32_t, t);
}

__global__ __launch_bounds__(256, 2) void attn_kernel(const __bf16* __restrict__ qkv,
                                                      __bf16* __restrict__ out) {
  __shared__ __align__(16) __bf16 Ks[2][64 * 128];   // XOR-swizzled 16B groups
  __shared__ __align__(16) __bf16 Vt[2][128][72];    // V^T, padded (stride 144B)
  const int tid = threadIdx.x;
  const int lane = tid & 63, l31 = lane & 31, hi = lane >> 5, wq = tid >> 6;
  const int head = blockIdx.x & 31;
  const int g = blockIdx.x >> 5;                     // 0..15
  const int qt = (g < 8) ? (15 - g) : (g - 8);       // LPT + slot pairing
  const int q0 = qt * 128;
  const int nt = 2 * qt + 2;                         // kv tiles (causal)
  const int kvh = head >> 2;
  const float sc2 = 0.08838834764831845f * 1.44269504089f;  // 1/sqrt(128)*log2(e)
  const int qr = q0 + wq * 32 + l31;                 // this lane's q row

  bf16x8 vr[2][2];  // in-flight V rows (2 tasks x 2 rows)

  auto stage_k = [&](int tt, int buf) {
#pragma unroll
    for (int i = 0; i < 4; ++i) {
      int c = i * 256 + tid;                         // 16B chunk 0..1023
      int r = c >> 4, gg = c & 15;
      const __bf16* gk = qkv + (size_t)(tt * 64 + r) * QKV_LD + KOFF + kvh * HD + ((gg ^ (r & 7)) * 8);
      __builtin_amdgcn_global_load_lds((gaddr_t)gk,
          (laddr_t)((char*)Ks[buf] + (tid & ~63) * 16 + i * 4096), 16, 0, 0);
    }
  };
  auto load_v = [&](int tt) {
#pragma unroll
    for (int i = 0; i < 2; ++i) {
      int task = i * 256 + tid;                      // 0..511
      int p = task >> 4, cg = task & 15;
      const __bf16* vp = qkv + (size_t)(tt * 64 + 2 * p) * QKV_LD + VOFF + kvh * HD + cg * 8;
      vr[i][0] = *reinterpret_cast<const bf16x8*>(vp);
      vr[i][1] = *reinterpret_cast<const bf16x8*>(vp + QKV_LD);
    }
  };
  auto write_v = [&](int buf) {
#pragma unroll
    for (int i = 0; i < 2; ++i) {
      int task = i * 256 + tid;
      int p = task >> 4, cg = task & 15;
#pragma unroll
      for (int e0 = 0; e0 < 8; ++e0) {
        int e = e0 ^ (lane & 7);
        bf16x2 pkv; pkv[0] = vr[i][0][e]; pkv[1] = vr[i][1][e];
        *reinterpret_cast<bf16x2*>(&Vt[buf][cg * 8 + e][2 * p]) = pkv;
      }
    }
  };

  // Q fragments (B-layout): lane holds Q[qr][k = ks*16 + hi*8 + 0..7]
  bf16x8 qf[8];
  {
    const __bf16* qp = qkv + (size_t)qr * QKV_LD + head * HD + hi * 8;
#pragma unroll
    for (int ks = 0; ks < 8; ++ks) qf[ks] = *reinterpret_cast<const bf16x8*>(qp + ks * 16);
  }
  f32x16 o[4] = {};
  float m_run = -3e38f, l_run = 0.f;

  stage_k(0, 0); load_v(0); write_v(0);

  for (int t = 0; t < nt; ++t) {
    const int cur = t & 1;
    __syncthreads();        // staging of buf[cur] visible; prev reads of buf[1-cur] done
    if (t + 1 < nt) { stage_k(t + 1, 1 - cur); load_v(t + 1); }

    // ---- S^T = K Q^T : col=q=l31, row=(e&3)+8*(e>>2)+4*hi
    f32x16 st[2];
#pragma unroll
    for (int sub = 0; sub < 2; ++sub) {
      f32x16 acc = {};
      int r = sub * 32 + l31;
#pragma unroll
      for (int ks = 0; ks < 8; ++ks) {
        int gg = (ks * 2 + hi) ^ (r & 7);
        bf16x8 kf = *reinterpret_cast<const bf16x8*>((char*)Ks[cur] + r * 256 + gg * 16);
        acc = __builtin_amdgcn_mfma_f32_32x32x16_bf16(kf, qf[ks], acc, 0, 0, 0);
      }
      st[sub] = acc;
    }
#pragma unroll
    for (int sub = 0; sub < 2; ++sub)
#pragma unroll
      for (int e = 0; e < 16; ++e) st[sub][e] *= sc2;
    if (t >= nt - 2) {      // only the two diagonal tiles need masking
      const int kv0 = t * 64;
#pragma unroll
      for (int sub = 0; sub < 2; ++sub)
#pragma unroll
        for (int e = 0; e < 16; ++e) {
          int kvg = kv0 + sub * 32 + (e & 3) + 8 * (e >> 2) + 4 * hi;
          if (kvg > qr) st[sub][e] = -1e30f;
        }
    }
    // ---- online softmax (lane-local, defer-max)
    float pm = st[0][0];
#pragma unroll
    for (int e = 1; e < 16; ++e) pm = fmaxf(pm, st[0][e]);
#pragma unroll
    for (int e = 0; e < 16; ++e) pm = fmaxf(pm, st[1][e]);
    pm = fmaxf(pm, __shfl_xor(pm, 32));
    if (!__all(pm - m_run <= 8.f)) {
      float mn = fmaxf(m_run, pm);
      float fsc = EXP2F(m_run - mn);
      m_run = mn;
      l_run *= fsc;
#pragma unroll
      for (int dt = 0; dt < 4; ++dt)
#pragma unroll
        for (int e = 0; e < 16; ++e) o[dt][e] *= fsc;
    }
    float rs = 0.f;
#pragma unroll
    for (int sub = 0; sub < 2; ++sub)
#pragma unroll
      for (int e = 0; e < 16; ++e) {
        float p = EXP2F(st[sub][e] - m_run);
        st[sub][e] = p;
        rs += p;
      }
    rs += __shfl_xor(rs, 32);
    l_run += rs;

    // ---- pack P to bf16 B-fragments: pf[tt] = P[qr][kv = tt*16 + hi*8 + 0..7]
    uint32_t pk[16];
#pragma unroll
    for (int sub = 0; sub < 2; ++sub)
#pragma unroll
      for (int i = 0; i < 8; ++i)
        pk[sub * 8 + i] = pack2(st[sub][2 * i], st[sub][2 * i + 1]);
    uint32_t rv[8];
#pragma unroll
    for (int m = 0; m < 8; ++m) {
      int base = 4 * (m >> 1) + (m & 1);
      uint32_t snd = hi ? pk[base] : pk[base + 2];
      rv[m] = __shfl_xor(snd, 32);
    }
    bf16x8 pf[4];
#pragma unroll
    for (int tt = 0; tt < 4; ++tt) {
      u32x4 wv;
      wv[0] = hi ? rv[2 * tt]     : pk[4 * tt];
      wv[1] = hi ? rv[2 * tt + 1] : pk[4 * tt + 1];
      wv[2] = hi ? pk[4 * tt + 2] : rv[2 * tt];
      wv[3] = hi ? pk[4 * tt + 3] : rv[2 * tt + 1];
      pf[tt] = __builtin_bit_cast(bf16x8, wv);
    }
    // ---- O^T += V^T P^T
#pragma unroll
    for (int dt = 0; dt < 4; ++dt) {
      int dr = dt * 32 + l31;
#pragma unroll
      for (int tt = 0; tt < 4; ++tt) {
        bf16x8 vf = *reinterpret_cast<const bf16x8*>((char*)&Vt[cur][0][0] + dr * 144 + tt * 32 + hi * 16);
        o[dt] = __builtin_amdgcn_mfma_f32_32x32x16_bf16(vf, pf[tt], o[dt], 0, 0, 0);
      }
    }
    // ---- late V^T write for next tile (loads had QK+softmax+PV to land)
    if (t + 1 < nt) write_v(1 - cur);
  }

  // ---- epilogue: transpose O^T -> O via per-wave LDS scratch, coalesced stores
  float inv = 1.f / l_run;
  __bf16* scr = &Ks[0][0] + wq * 1280;               // [32][40] bf16 per wave
  const int qq = lane >> 1, part = lane & 1;
#pragma unroll
  for (int dt = 0; dt < 4; ++dt) {
    __syncthreads();                                 // all waves done reading Ks/Vt (or prev dt)
#pragma unroll
    for (int i = 0; i < 8; ++i) {
      int d0 = (2 * i & 3) + 8 * (i >> 1) + 4 * hi;
      bf16x2 prr;
      prr[0] = (__bf16)(o[dt][2 * i] * inv);
      prr[1] = (__bf16)(o[dt][2 * i + 1] * inv);
      *reinterpret_cast<bf16x2*>(scr + l31 * 40 + d0) = prr;
    }
    __syncthreads();
    bf16x8 r0 = *reinterpret_cast<const bf16x8*>(scr + qq * 40 + part * 16);
    bf16x8 r1 = *reinterpret_cast<const bf16x8*>(scr + qq * 40 + part * 16 + 8);
    __bf16* op = out + (size_t)(q0 + wq * 32 + qq) * DIM_ + head * HD + dt * 32 + part * 16;
    *reinterpret_cast<bf16x8*>(op) = r0;
    *reinterpret_cast<bf16x8*>(op + 8) = r1;
  }
}

// ---------------------------------------------------------------------------
extern "C" void kernel_launch(void* const* d_in, const int* in_sizes, int n_in,
                              void* d_out, int out_size, void* d_ws, size_t ws_size,
                              hipStream_t stream) {
  (void)in_sizes; (void)n_in; (void)out_size; (void)ws_size;
  const float* x    = (const float*)d_in[0];
  const float* fc   = (const float*)d_in[1];
  const float* fs   = (const float*)d_in[2];
  // d_in[3] = mask (causal, hardcoded in attn_kernel)
  const float* wqkv = (const float*)d_in[4];
  const float* wo   = (const float*)d_in[5];
  float* out = (float*)d_out;

  char* ws = (char*)d_ws;
  __bf16* xb    = (__bf16*)(ws);                       // 16,777,216  (reused as attn_out)
  __bf16* wqkvb = (__bf16*)(ws + 16777216);            // 50,331,648
  __bf16* wob   = (__bf16*)(ws + 67108864);            // 33,554,432
  __bf16* qkv   = (__bf16*)(ws + 100663296);           // 25,165,824
  __bf16* attnO = xb;                                  // xb dead after gemm1

  cvt_f32_bf16<<<2048, 256, 0, stream>>>(x,    xb,    (S_LEN * DIM_) / 4);
  cvt_f32_bf16<<<2048, 256, 0, stream>>>(wqkv, wqkvb, (6144 * DIM_) / 4);
  cvt_f32_bf16<<<2048, 256, 0, stream>>>(wo,   wob,   (DIM_ * DIM_) / 4);

  // qkv = x @ wqkv^T : M=2048, N=6144, K=4096. 256x256 tiles -> 8x24 = 192 blocks.
  // Per-XCD chunk 8M x 3N (m = lid%8, n = xcd*3 + lid/8).
  gemm8p<256, 256, 8, 3, __bf16><<<192, 512, 0, stream>>>(xb, wqkvb, qkv, DIM_, DIM_, DIM_, QKV_LD);

  // rope on Q + K parts
  rope_kernel<<<(S_LEN * 40 * 64) / 256, 256, 0, stream>>>(qkv, fc, fs);

  // causal GQA attention (512 blocks x 256 threads, 2 blocks/CU, paired LPT)
  attn_kernel<<<512, 256, 0, stream>>>(qkv, attnO);

  // out = attnO @ wo^T : M=2048, N=4096, K=4096. 128x256 tiles -> 16x16 = 256 blocks.
  // Per-XCD chunk 16M x 2N (m = lid%16, n = xcd*2 + lid/16).
  gemm8p<128, 256, 16, 2, float><<<256, 512, 0, stream>>>(attnO, wob, out, DIM_, DIM_, DIM_, DIM_);
}